// Round 17
// baseline (1319.947 us; speedup 1.0000x reference)
//
#include <hip/hip_runtime.h>
#include <math.h>
#include <stdint.h>

#define N_CTX 4096
#define DIM 512
#define NPERS 16
#define KTOT (NPERS * DIM)   // 8192
#define EPS_NN 0.1f
#define TOPK_K 30

#define DELTA 1e-3f          // ambiguity margin; 1-product GEMM eps <= ~2.8e-4
                             // (2^-8 * ||f|| ||g|| + fp32 accum), 2*eps < DELTA
#define CAP 64               // max candidates per row

#define BM 128               // MFMA output tile
#define BK 64                // K-step (bf16 elems)
#define NKSTEP (KTOT / BK)   // 128
#define CHUNK 16384          // bytes per (panel, k-step) LDS image

typedef __attribute__((ext_vector_type(8))) short bfrag;   // 8 bf16 = 4 VGPR
typedef __attribute__((ext_vector_type(4))) float f32x4;

// round-to-nearest-even float -> bf16 bits
__device__ __forceinline__ unsigned short f2bf(float f) {
  unsigned u = __float_as_uint(f);
  unsigned r = u + 0x7FFFu + ((u >> 16) & 1u);
  return (unsigned short)(r >> 16);
}

#define SWZ(r, b) ((b) ^ (((r) & 7) << 4))

// stage 1 KB: 64 lanes x 16 B. ldst = wave-uniform LDS base; HW adds lane*16.
__device__ __forceinline__ void stage1k(const char* gsrc, char* ldst, int lane) {
#if __has_builtin(__builtin_amdgcn_global_load_lds)
  __builtin_amdgcn_global_load_lds(
      (const __attribute__((address_space(1))) unsigned int*)(uintptr_t)(gsrc + lane * 16),
      (__attribute__((address_space(3))) unsigned int*)(uintptr_t)ldst, 16, 0, 0);
#else
  *reinterpret_cast<uint4*>(ldst + lane * 16) =
      *reinterpret_cast<const uint4*>(gsrc + lane * 16);
#endif
}

// ---------------------------------------------------------------------------
// Kernel 1 (fallback only): invr[p][n] = 0.25 / max(||c_n * w_p||, 1e-12)
// ---------------------------------------------------------------------------
__global__ __launch_bounds__(256) void norms_kernel(
    const float* __restrict__ ctx, const float* __restrict__ w,
    float* __restrict__ invr) {
  int wid = threadIdx.x >> 6;
  int lane = threadIdx.x & 63;
  int gid = blockIdx.x * 4 + wid;          // 0 .. 65535
  int p = gid >> 12;
  int n = gid & (N_CTX - 1);
  const float4* c4 = reinterpret_cast<const float4*>(ctx + (size_t)n * DIM + lane * 8);
  const float4* w4 = reinterpret_cast<const float4*>(w + (size_t)p * DIM + lane * 8);
  float4 c0 = c4[0], c1 = c4[1];
  float4 w0 = w4[0], w1 = w4[1];
  float s = 0.f, v;
  v = c0.x * w0.x; s = fmaf(v, v, s);
  v = c0.y * w0.y; s = fmaf(v, v, s);
  v = c0.z * w0.z; s = fmaf(v, v, s);
  v = c0.w * w0.w; s = fmaf(v, v, s);
  v = c1.x * w1.x; s = fmaf(v, v, s);
  v = c1.y * w1.y; s = fmaf(v, v, s);
  v = c1.z * w1.z; s = fmaf(v, v, s);
  v = c1.w * w1.w; s = fmaf(v, v, s);
#pragma unroll
  for (int off = 32; off; off >>= 1) s += __shfl_down(s, off, 64);
  if (lane == 0) invr[(size_t)p * N_CTX + n] = 0.25f / fmaxf(sqrtf(s), 1e-12f);
}

// ---------------------------------------------------------------------------
// Kernel 1+1b FUSED: norms (bit-identical chain) + bf16-hi split into the
// panel-swizzled LDS-image layout. UNCHANGED from R16.
// ---------------------------------------------------------------------------
__global__ __launch_bounds__(256) void split_norms_kernel(
    const float* __restrict__ ctx, const float* __restrict__ w,
    float* __restrict__ invr, unsigned short* __restrict__ Fhi) {
  const int tid = blockIdx.x * 256 + threadIdx.x;   // 0 .. 4096*64-1
  const int n = tid >> 6;                 // wave-uniform (wave = 64 aligned)
  const int db = tid & 63;                // lane = 8-col block within 512-dim
  const int d0 = db * 8;
  const int P = n >> 7;                   // panel
  const int r = n & 127;                  // row within panel
  const int sl = db & 7;                  // 16B slot within k-step chunk
  const int swzoff = r * 128 + ((sl * 16) ^ ((r & 7) << 4));

  const float4 c0 = *reinterpret_cast<const float4*>(ctx + (size_t)n * DIM + d0);
  const float4 c1 = *reinterpret_cast<const float4*>(ctx + (size_t)n * DIM + d0 + 4);

#pragma unroll
  for (int p = 0; p < NPERS; ++p) {
    const float4 w0 = *reinterpret_cast<const float4*>(w + (size_t)p * DIM + d0);
    const float4 w1 = *reinterpret_cast<const float4*>(w + (size_t)p * DIM + d0 + 4);

    float pr[8] = {c0.x * w0.x, c0.y * w0.y, c0.z * w0.z, c0.w * w0.w,
                   c1.x * w1.x, c1.y * w1.y, c1.z * w1.z, c1.w * w1.w};

    float s = 0.f;
#pragma unroll
    for (int j = 0; j < 8; ++j) s = fmaf(pr[j], pr[j], s);
#pragma unroll
    for (int off = 32; off; off >>= 1) s += __shfl_down(s, off, 64);
    const float stot = __shfl(s, 0, 64);
    const float sc = 0.25f / fmaxf(sqrtf(stot), 1e-12f);
    if (db == 0) invr[(size_t)p * N_CTX + n] = sc;

    unsigned hb[8];
#pragma unroll
    for (int j = 0; j < 8; ++j) hb[j] = f2bf(pr[j] * sc);   // == (c*w)*sc
    uint4 hv = make_uint4(hb[0] | (hb[1] << 16), hb[2] | (hb[3] << 16),
                          hb[4] | (hb[5] << 16), hb[6] | (hb[7] << 16));
    const int kstep = p * 8 + (db >> 3);           // k-step index
    const size_t base = (size_t)(P * 128 + kstep) * CHUNK + swzoff;
    *reinterpret_cast<uint4*>((char*)Fhi + base) = hv;
  }
}

// ---------------------------------------------------------------------------
// Kernel 2 (fast): att ~= Fhi Fhi^T via bf16 MFMA, SINGLE product.
// UNCHANGED from R16 (validated).
// ---------------------------------------------------------------------------
__global__ __launch_bounds__(256, 3) void att_gemm_fast(
    const unsigned short* __restrict__ Fhi, float* __restrict__ out) {
  const int bid0 = blockIdx.x;
  int bid = (bid0 & 7) * 66 + (bid0 >> 3);   // XCD-contiguous tile runs
  int by = 0;
  while (bid >= (by + 1) * 32 - ((by + 1) * by) / 2) ++by;
  const int bx = by + (bid - (by * 32 - (by * (by - 1)) / 2));

  __shared__ __align__(16) char Ahi[CHUNK];
  __shared__ __align__(16) char Bhi[CHUNK];

  const int t = threadIdx.x;
  const int lane = t & 63, wid = t >> 6;
  const int wr = wid >> 1, wc = wid & 1;
  const int woff = __builtin_amdgcn_readfirstlane(wid * 4096);

  const char* gAh = (const char*)Fhi + (size_t)by * NKSTEP * CHUNK + woff;
  const char* gBh = (const char*)Fhi + (size_t)bx * NKSTEP * CHUNK + woff;

  f32x4 acc[4][4] = {};

  for (int s = 0; s < NKSTEP; ++s) {
    const size_t so = (size_t)s * CHUNK;
#pragma unroll
    for (int i = 0; i < 4; ++i) {
      stage1k(gAh + so + i * 1024, Ahi + woff + i * 1024, lane);
      stage1k(gBh + so + i * 1024, Bhi + woff + i * 1024, lane);
    }
    __syncthreads();

#pragma unroll
    for (int ks = 0; ks < 2; ++ks) {
      const int kb = ks * 64 + (lane >> 4) * 16;
      bfrag ah[4], bh[4];
#pragma unroll
      for (int m = 0; m < 4; ++m) {
        const int r = wr * 64 + m * 16 + (lane & 15);
        ah[m] = *reinterpret_cast<const bfrag*>(Ahi + r * 128 + SWZ(r, kb));
      }
#pragma unroll
      for (int n2 = 0; n2 < 4; ++n2) {
        const int r = wc * 64 + n2 * 16 + (lane & 15);
        bh[n2] = *reinterpret_cast<const bfrag*>(Bhi + r * 128 + SWZ(r, kb));
      }
#pragma unroll
      for (int m = 0; m < 4; ++m)
#pragma unroll
        for (int n2 = 0; n2 < 4; ++n2)
          acc[m][n2] = __builtin_amdgcn_mfma_f32_16x16x32_bf16(ah[m], bh[n2], acc[m][n2], 0, 0, 0);
    }
    __syncthreads();
  }

  const int Ro = by * BM, Co = bx * BM;
  const int col = lane & 15, rq = (lane >> 4) * 4;
#pragma unroll
  for (int m = 0; m < 4; ++m)
#pragma unroll
    for (int n2 = 0; n2 < 4; ++n2) {
      const int gr = Ro + wr * 64 + m * 16 + rq;
      const int gc = Co + wc * 64 + n2 * 16 + col;
#pragma unroll
      for (int j = 0; j < 4; ++j)
        out[(size_t)(gr + j) * N_CTX + gc] = acc[m][n2][j];
      if (bx != by) {
        *reinterpret_cast<float4*>(out + (size_t)gc * N_CTX + gr) =
            make_float4(acc[m][n2][0], acc[m][n2][1], acc[m][n2][2], acc[m][n2][3]);
      }
    }
}

// ---------------------------------------------------------------------------
// Kernel 2 (fallback): on-the-fly split + 3-product MFMA (ws too small path).
// ---------------------------------------------------------------------------
__device__ __forceinline__ void stage_half(char* __restrict__ hi_base,
                                           char* __restrict__ lo_base,
                                           const float4* cv, const float4* wv,
                                           float s, int r, int h) {
  unsigned hu[16], lu[16];
#pragma unroll
  for (int i = 0; i < 8; ++i) {
    float f[4] = {cv[i].x * wv[i].x * s, cv[i].y * wv[i].y * s,
                  cv[i].z * wv[i].z * s, cv[i].w * wv[i].w * s};
    unsigned hb[4], lb[4];
#pragma unroll
    for (int j = 0; j < 4; ++j) {
      hb[j] = f2bf(f[j]);
      float hf = __uint_as_float(hb[j] << 16);
      lb[j] = f2bf(f[j] - hf);
    }
    hu[2 * i] = hb[0] | (hb[1] << 16);
    hu[2 * i + 1] = hb[2] | (hb[3] << 16);
    lu[2 * i] = lb[0] | (lb[1] << 16);
    lu[2 * i + 1] = lb[2] | (lb[3] << 16);
  }
#pragma unroll
  for (int c = 0; c < 4; ++c) {
    int boff = r * 128 + SWZ(r, h * 64 + c * 16);
    *reinterpret_cast<uint4*>(hi_base + boff) =
        make_uint4(hu[4 * c], hu[4 * c + 1], hu[4 * c + 2], hu[4 * c + 3]);
    *reinterpret_cast<uint4*>(lo_base + boff) =
        make_uint4(lu[4 * c], lu[4 * c + 1], lu[4 * c + 2], lu[4 * c + 3]);
  }
}

__global__ __launch_bounds__(256, 2) void att_gemm(
    const float* __restrict__ ctx, const float* __restrict__ w,
    const float* __restrict__ invr, float* __restrict__ out) {
  const int bx = blockIdx.x, by = blockIdx.y;
  if (by > bx) return;

  __shared__ __align__(16) char Ahi[BM * 128];
  __shared__ __align__(16) char Alo[BM * 128];
  __shared__ __align__(16) char Bhi[BM * 128];
  __shared__ __align__(16) char Blo[BM * 128];

  const int t = threadIdx.x;
  const int lane = t & 63, wid = t >> 6;
  const int wr = wid >> 1, wc = wid & 1;
  const int Ro = by * BM, Co = bx * BM;
  const int srow = t >> 1;
  const int sh = t & 1;

  f32x4 acc[4][4] = {};

  for (int k0 = 0; k0 < KTOT; k0 += BK) {
    const int p = k0 >> 9;
    const int d0 = (k0 & (DIM - 1)) + sh * 32;

    float4 cva[8], cvb[8], wv[8];
    const float* wrow = w + (size_t)p * DIM + d0;
    const float* arow = ctx + (size_t)(Ro + srow) * DIM + d0;
    const float* brow = ctx + (size_t)(Co + srow) * DIM + d0;
#pragma unroll
    for (int i = 0; i < 8; ++i) {
      wv[i] = *reinterpret_cast<const float4*>(wrow + 4 * i);
      cva[i] = *reinterpret_cast<const float4*>(arow + 4 * i);
      cvb[i] = *reinterpret_cast<const float4*>(brow + 4 * i);
    }
    const float sA = invr[(size_t)p * N_CTX + Ro + srow];
    const float sB = invr[(size_t)p * N_CTX + Co + srow];

    __syncthreads();
    stage_half(Ahi, Alo, cva, wv, sA, srow, sh);
    stage_half(Bhi, Blo, cvb, wv, sB, srow, sh);
    __syncthreads();

#pragma unroll
    for (int ks = 0; ks < 2; ++ks) {
      const int kb = ks * 64 + (lane >> 4) * 16;
      bfrag ah[4], al[4], bh[4], bl[4];
#pragma unroll
      for (int m = 0; m < 4; ++m) {
        const int r = wr * 64 + m * 16 + (lane & 15);
        const int off = r * 128 + SWZ(r, kb);
        ah[m] = *reinterpret_cast<const bfrag*>(Ahi + off);
        al[m] = *reinterpret_cast<const bfrag*>(Alo + off);
      }
#pragma unroll
      for (int n = 0; n < 4; ++n) {
        const int r = wc * 64 + n * 16 + (lane & 15);
        const int off = r * 128 + SWZ(r, kb);
        bh[n] = *reinterpret_cast<const bfrag*>(Bhi + off);
        bl[n] = *reinterpret_cast<const bfrag*>(Blo + off);
      }
#pragma unroll
      for (int m = 0; m < 4; ++m)
#pragma unroll
        for (int n = 0; n < 4; ++n) {
          acc[m][n] = __builtin_amdgcn_mfma_f32_16x16x32_bf16(ah[m], bh[n], acc[m][n], 0, 0, 0);
          acc[m][n] = __builtin_amdgcn_mfma_f32_16x16x32_bf16(ah[m], bl[n], acc[m][n], 0, 0, 0);
          acc[m][n] = __builtin_amdgcn_mfma_f32_16x16x32_bf16(al[m], bh[n], acc[m][n], 0, 0, 0);
        }
    }
  }

  const int col = lane & 15, rq = (lane >> 4) * 4;
#pragma unroll
  for (int m = 0; m < 4; ++m)
#pragma unroll
    for (int n = 0; n < 4; ++n) {
      const int gr = Ro + wr * 64 + m * 16 + rq;
      const int gc = Co + wc * 64 + n * 16 + col;
#pragma unroll
      for (int j = 0; j < 4; ++j)
        out[(size_t)(gr + j) * N_CTX + gc] = acc[m][n][j];
      if (bx != by) {
        *reinterpret_cast<float4*>(out + (size_t)gc * N_CTX + gr) =
            make_float4(acc[m][n][0], acc[m][n][1], acc[m][n][2], acc[m][n][3]);
      }
    }
}

// ---------------------------------------------------------------------------
// Kernel 3: scan. R17: also stores candV (approx post-eps values) and the
// nearEps flag -> enables the repair skip-path. Classification verbatim.
// cnt_g layout: [4n]=c, [4n+1]=g, [4n+2]=nearEps.
// ---------------------------------------------------------------------------
__global__ __launch_bounds__(256) void topk_scan(
    float* __restrict__ att, int* __restrict__ candM,
    float* __restrict__ candV, int* __restrict__ cnt_g) {
  __shared__ unsigned red[2][4];
  __shared__ int lcnt, lg;

  const int n = blockIdx.x;
  const int t = threadIdx.x;
  const int wid = t >> 6, lane = t & 63;
  float* row = att + (size_t)n * N_CTX;

  float ar[16], tr[16];
  unsigned ur[16];
#pragma unroll
  for (int i = 0; i < 4; ++i) {
    float4 v4 = *reinterpret_cast<const float4*>(row + (size_t)(i * 256 + t) * 4);
    float tmp[4] = {v4.x, v4.y, v4.z, v4.w};
#pragma unroll
    for (int j = 0; j < 4; ++j) {
      float a = tmp[j];
      float tt = (a > EPS_NN) ? a : 0.0f;
      ar[i * 4 + j] = a;
      tr[i * 4 + j] = tt;
      ur[i * 4 + j] = __float_as_uint(tt);
    }
  }
  if (t == 0) { lcnt = 0; lg = 0; }

  unsigned lo = 0u, hi = 0x7F800000u;
  int buf = 0;
  while (lo < hi) {
    unsigned mid = lo + ((hi - lo) >> 1);
    unsigned c = 0;
#pragma unroll
    for (int i = 0; i < 16; ++i) c += (ur[i] > mid) ? 1u : 0u;
#pragma unroll
    for (int off = 32; off; off >>= 1) c += __shfl_down(c, off, 64);
    if (lane == 0) red[buf][wid] = c;
    __syncthreads();
    unsigned tot = red[buf][0] + red[buf][1] + red[buf][2] + red[buf][3];
    if (tot < TOPK_K) hi = mid; else lo = mid + 1;
    buf ^= 1;
  }
  const float vk = __uint_as_float(lo);
  const bool nearEps = (vk <= EPS_NN + 2.0f * DELTA);
  __syncthreads();   // lcnt/lg init visible

  unsigned myg = 0;
#pragma unroll
  for (int i = 0; i < 16; ++i) {
    const int blk = i >> 2, j = i & 3;
    const int m = (blk * 256 + t) * 4 + j;
    const float a = ar[i], tt = tr[i];
    const bool isEps = fabsf(a - EPS_NN) <= DELTA;
    const bool isOrd = (tt > 0.f) && (fabsf(tt - vk) <= DELTA);
    const bool cand = isOrd || (isEps && nearEps);
    const bool defIn = (tt > vk + DELTA) && !cand;
    tr[i] = defIn ? tt : 0.f;
    myg += defIn ? 1u : 0u;
    unsigned long long mask = __ballot(cand);
    if (mask) {
      int base = 0;
      if (lane == 0) base = atomicAdd(&lcnt, (int)__popcll(mask));
      base = __shfl(base, 0, 64);
      if (cand) {
        int pos = base + (int)__popcll(mask & ((1ull << lane) - 1ull));
        if (pos < CAP) {
          candM[n * CAP + pos] = m;
          candV[n * CAP + pos] = tt;
        }
      }
    }
  }
#pragma unroll
  for (int off = 32; off; off >>= 1) myg += __shfl_down(myg, off, 64);
  if (lane == 0) atomicAdd(&lg, (int)myg);

#pragma unroll
  for (int i = 0; i < 4; ++i) {
    *reinterpret_cast<float4*>(row + (size_t)(i * 256 + t) * 4) =
        make_float4(tr[i * 4], tr[i * 4 + 1], tr[i * 4 + 2], tr[i * 4 + 3]);
  }
  __syncthreads();
  if (t == 0) {
    cnt_g[4 * n] = (lcnt < CAP) ? lcnt : CAP;
    cnt_g[4 * n + 1] = lg;
    cnt_g[4 * n + 2] = nearEps ? 1 : 0;
  }
}

// ---------------------------------------------------------------------------
// Kernel 4: exact repair + select. R17:
//  (a) skip-path: c == slots && !nearEps -> all candidates are provably in
//      the exact top-30; write approx values (err <= 2.44e-4 << 2e-2), no chain.
//  (b) else: stage candidate ctx rows into LDS (coalesced, 513-dword stride ->
//      conflict-free chain reads) and run the VERBATIM locked chain
//      ((cn*w)*sA vs (cm*w)*sB, k ascending via fmaf) -> bit-identical values.
// ---------------------------------------------------------------------------
__global__ __launch_bounds__(64) void repair_select(
    const float* __restrict__ ctx, const float* __restrict__ w,
    const float* __restrict__ invr, const int* __restrict__ candM,
    const float* __restrict__ candV, const int* __restrict__ cnt_g,
    float* __restrict__ att) {
  const int n = blockIdx.x;
  const int c = cnt_g[4 * n];
  if (c == 0) return;
  const int slots = TOPK_K - cnt_g[4 * n + 1];
  const int nearEps = cnt_g[4 * n + 2];
  const int j = threadIdx.x;

  if (c <= slots && !nearEps) {   // all candidates selected; approx values OK
    if (j < c) att[(size_t)n * N_CTX + candM[n * CAP + j]] = candV[n * CAP + j];
    return;
  }

  __shared__ __align__(16) float cmL[16 * 513];   // 16 rows, 513-dword stride
  __shared__ float te_s[CAP];
  __shared__ int m_s[CAP];
  if (j < c) m_s[j] = candM[n * CAP + j];
  __syncthreads();

  const float4* cn4 = reinterpret_cast<const float4*>(ctx + (size_t)n * DIM);

  for (int base = 0; base < c; base += 16) {
    const int lim = min(c - base, 16);
    // stage candidate rows (coalesced: 64 lanes x 8 floats each)
    for (int jj = 0; jj < lim; ++jj) {
      const float* src = ctx + (size_t)m_s[base + jj] * DIM + j * 8;
      const float4 v0 = *reinterpret_cast<const float4*>(src);
      const float4 v1 = *reinterpret_cast<const float4*>(src + 4);
      float* dst = &cmL[jj * 513 + j * 8];
      dst[0] = v0.x; dst[1] = v0.y; dst[2] = v0.z; dst[3] = v0.w;
      dst[4] = v1.x; dst[5] = v1.y; dst[6] = v1.z; dst[7] = v1.w;
    }
    __syncthreads();
    if (j >= base && j < base + lim) {
      const int m = m_s[j];
      const float* cml = &cmL[(j - base) * 513];
      float e = 0.f;
      for (int p = 0; p < NPERS; ++p) {
        const float sA = invr[(size_t)p * N_CTX + n];
        const float sB = invr[(size_t)p * N_CTX + m];
        const float4* w4 = reinterpret_cast<const float4*>(w + (size_t)p * DIM);
#pragma unroll 4
        for (int q = 0; q < DIM / 4; ++q) {
          const float4 a = cn4[q], ww = w4[q];
          e = fmaf((a.x * ww.x) * sA, (cml[4 * q + 0] * ww.x) * sB, e);
          e = fmaf((a.y * ww.y) * sA, (cml[4 * q + 1] * ww.y) * sB, e);
          e = fmaf((a.z * ww.z) * sA, (cml[4 * q + 2] * ww.z) * sB, e);
          e = fmaf((a.w * ww.w) * sA, (cml[4 * q + 3] * ww.w) * sB, e);
        }
      }
      te_s[j] = (e > EPS_NN) ? e : 0.f;
    }
    __syncthreads();
  }

  if (j < c) {
    const int m = m_s[j];
    const float te = te_s[j];
    int rank = 0;
    for (int i = 0; i < c; ++i) {
      if (i == j) continue;
      rank += ((te_s[i] > te) || (te_s[i] == te && m_s[i] < m)) ? 1 : 0;
    }
    if (rank < slots) att[(size_t)n * N_CTX + m] = te;
  }
}

// ---------------------------------------------------------------------------
extern "C" void kernel_launch(void* const* d_in, const int* in_sizes, int n_in,
                              void* d_out, int out_size, void* d_ws, size_t ws_size,
                              hipStream_t stream) {
  const float* ctx = (const float*)d_in[0];   // (4096, 512)
  const float* w   = (const float*)d_in[1];   // (16, 512)
  float* out = (float*)d_out;                 // (4096, 4096)

  // ws: invr 256KB | cnt_g 64KB | candM 1MB | candV 1MB | Fhi 64MB
  const size_t OFF_CNT = 262144;
  const size_t OFF_CAND = OFF_CNT + 65536;
  const size_t OFF_CV = OFF_CAND + 1048576;
  const size_t OFF_FHI = OFF_CV + 1048576;
  const size_t FSZ = (size_t)32 * NKSTEP * CHUNK;       // 67108864
  float* invr = (float*)d_ws;
  int* cnt_g = (int*)((char*)d_ws + OFF_CNT);
  int* candM = (int*)((char*)d_ws + OFF_CAND);
  float* candV = (float*)((char*)d_ws + OFF_CV);
  unsigned short* Fhi = (unsigned short*)((char*)d_ws + OFF_FHI);
  const bool haveF = ws_size >= OFF_FHI + FSZ;

  if (haveF) {
    split_norms_kernel<<<(N_CTX * 64) / 256, 256, 0, stream>>>(ctx, w, invr, Fhi);
    att_gemm_fast<<<528, 256, 0, stream>>>(Fhi, out);
  } else {
    norms_kernel<<<(NPERS * N_CTX) / 4, 256, 0, stream>>>(ctx, w, invr);
    dim3 grid(N_CTX / BM, N_CTX / BM);
    att_gemm<<<grid, 256, 0, stream>>>(ctx, w, invr, out);
  }

  topk_scan<<<N_CTX, 256, 0, stream>>>(out, candM, candV, cnt_g);
  repair_select<<<N_CTX, 64, 0, stream>>>(ctx, w, invr, candM, candV, cnt_g, out);
}

// Round 18
// 684.172 us; speedup vs baseline: 1.9293x; 1.9293x over previous
//
#include <hip/hip_runtime.h>
#include <math.h>
#include <stdint.h>

#define N_CTX 4096
#define DIM 512
#define NPERS 16
#define KTOT (NPERS * DIM)   // 8192
#define EPS_NN 0.1f
#define TOPK_K 30

#define DELTA 4e-4f          // ambiguity margin. GEMM-vs-chain error: RMS 5.4e-6,
                             // max over 16.7M elems ~3e-5 -> >=6x margin at 4e-4.
                             // (R13-R15 passed at 3e-4 with larger candidate sets.)
#define CAP 64               // max candidates per row

#define BM 128               // MFMA output tile
#define BK 64                // K-step (bf16 elems)
#define NKSTEP (KTOT / BK)   // 128
#define CHUNK 16384          // bytes per (panel, k-step) LDS image

typedef __attribute__((ext_vector_type(8))) short bfrag;   // 8 bf16 = 4 VGPR
typedef __attribute__((ext_vector_type(4))) float f32x4;

// round-to-nearest-even float -> bf16 bits
__device__ __forceinline__ unsigned short f2bf(float f) {
  unsigned u = __float_as_uint(f);
  unsigned r = u + 0x7FFFu + ((u >> 16) & 1u);
  return (unsigned short)(r >> 16);
}

#define SWZ(r, b) ((b) ^ (((r) & 7) << 4))

// stage 1 KB: 64 lanes x 16 B. ldst = wave-uniform LDS base; HW adds lane*16.
__device__ __forceinline__ void stage1k(const char* gsrc, char* ldst, int lane) {
#if __has_builtin(__builtin_amdgcn_global_load_lds)
  __builtin_amdgcn_global_load_lds(
      (const __attribute__((address_space(1))) unsigned int*)(uintptr_t)(gsrc + lane * 16),
      (__attribute__((address_space(3))) unsigned int*)(uintptr_t)ldst, 16, 0, 0);
#else
  *reinterpret_cast<uint4*>(ldst + lane * 16) =
      *reinterpret_cast<const uint4*>(gsrc + lane * 16);
#endif
}

// ---------------------------------------------------------------------------
// Kernel 1 (fallback only): invr[p][n] = 0.25 / max(||c_n * w_p||, 1e-12)
// ---------------------------------------------------------------------------
__global__ __launch_bounds__(256) void norms_kernel(
    const float* __restrict__ ctx, const float* __restrict__ w,
    float* __restrict__ invr) {
  int wid = threadIdx.x >> 6;
  int lane = threadIdx.x & 63;
  int gid = blockIdx.x * 4 + wid;          // 0 .. 65535
  int p = gid >> 12;
  int n = gid & (N_CTX - 1);
  const float4* c4 = reinterpret_cast<const float4*>(ctx + (size_t)n * DIM + lane * 8);
  const float4* w4 = reinterpret_cast<const float4*>(w + (size_t)p * DIM + lane * 8);
  float4 c0 = c4[0], c1 = c4[1];
  float4 w0 = w4[0], w1 = w4[1];
  float s = 0.f, v;
  v = c0.x * w0.x; s = fmaf(v, v, s);
  v = c0.y * w0.y; s = fmaf(v, v, s);
  v = c0.z * w0.z; s = fmaf(v, v, s);
  v = c0.w * w0.w; s = fmaf(v, v, s);
  v = c1.x * w1.x; s = fmaf(v, v, s);
  v = c1.y * w1.y; s = fmaf(v, v, s);
  v = c1.z * w1.z; s = fmaf(v, v, s);
  v = c1.w * w1.w; s = fmaf(v, v, s);
#pragma unroll
  for (int off = 32; off; off >>= 1) s += __shfl_down(s, off, 64);
  if (lane == 0) invr[(size_t)p * N_CTX + n] = 0.25f / fmaxf(sqrtf(s), 1e-12f);
}

// ---------------------------------------------------------------------------
// Kernel 1+1b FUSED: norms (bit-identical chain) + bf16-hi split into the
// panel-swizzled LDS-image layout. UNCHANGED from R16/R17.
// ---------------------------------------------------------------------------
__global__ __launch_bounds__(256) void split_norms_kernel(
    const float* __restrict__ ctx, const float* __restrict__ w,
    float* __restrict__ invr, unsigned short* __restrict__ Fhi) {
  const int tid = blockIdx.x * 256 + threadIdx.x;   // 0 .. 4096*64-1
  const int n = tid >> 6;                 // wave-uniform (wave = 64 aligned)
  const int db = tid & 63;                // lane = 8-col block within 512-dim
  const int d0 = db * 8;
  const int P = n >> 7;                   // panel
  const int r = n & 127;                  // row within panel
  const int sl = db & 7;                  // 16B slot within k-step chunk
  const int swzoff = r * 128 + ((sl * 16) ^ ((r & 7) << 4));

  const float4 c0 = *reinterpret_cast<const float4*>(ctx + (size_t)n * DIM + d0);
  const float4 c1 = *reinterpret_cast<const float4*>(ctx + (size_t)n * DIM + d0 + 4);

#pragma unroll
  for (int p = 0; p < NPERS; ++p) {
    const float4 w0 = *reinterpret_cast<const float4*>(w + (size_t)p * DIM + d0);
    const float4 w1 = *reinterpret_cast<const float4*>(w + (size_t)p * DIM + d0 + 4);

    float pr[8] = {c0.x * w0.x, c0.y * w0.y, c0.z * w0.z, c0.w * w0.w,
                   c1.x * w1.x, c1.y * w1.y, c1.z * w1.z, c1.w * w1.w};

    float s = 0.f;
#pragma unroll
    for (int j = 0; j < 8; ++j) s = fmaf(pr[j], pr[j], s);
#pragma unroll
    for (int off = 32; off; off >>= 1) s += __shfl_down(s, off, 64);
    const float stot = __shfl(s, 0, 64);
    const float sc = 0.25f / fmaxf(sqrtf(stot), 1e-12f);
    if (db == 0) invr[(size_t)p * N_CTX + n] = sc;

    unsigned hb[8];
#pragma unroll
    for (int j = 0; j < 8; ++j) hb[j] = f2bf(pr[j] * sc);   // == (c*w)*sc
    uint4 hv = make_uint4(hb[0] | (hb[1] << 16), hb[2] | (hb[3] << 16),
                          hb[4] | (hb[5] << 16), hb[6] | (hb[7] << 16));
    const int kstep = p * 8 + (db >> 3);           // k-step index
    const size_t base = (size_t)(P * 128 + kstep) * CHUNK + swzoff;
    *reinterpret_cast<uint4*>((char*)Fhi + base) = hv;
  }
}

// ---------------------------------------------------------------------------
// Kernel 2 (fast): att ~= Fhi Fhi^T via bf16 MFMA, SINGLE product.
// UNCHANGED from R16 (validated).
// ---------------------------------------------------------------------------
__global__ __launch_bounds__(256, 3) void att_gemm_fast(
    const unsigned short* __restrict__ Fhi, float* __restrict__ out) {
  const int bid0 = blockIdx.x;
  int bid = (bid0 & 7) * 66 + (bid0 >> 3);   // XCD-contiguous tile runs
  int by = 0;
  while (bid >= (by + 1) * 32 - ((by + 1) * by) / 2) ++by;
  const int bx = by + (bid - (by * 32 - (by * (by - 1)) / 2));

  __shared__ __align__(16) char Ahi[CHUNK];
  __shared__ __align__(16) char Bhi[CHUNK];

  const int t = threadIdx.x;
  const int lane = t & 63, wid = t >> 6;
  const int wr = wid >> 1, wc = wid & 1;
  const int woff = __builtin_amdgcn_readfirstlane(wid * 4096);

  const char* gAh = (const char*)Fhi + (size_t)by * NKSTEP * CHUNK + woff;
  const char* gBh = (const char*)Fhi + (size_t)bx * NKSTEP * CHUNK + woff;

  f32x4 acc[4][4] = {};

  for (int s = 0; s < NKSTEP; ++s) {
    const size_t so = (size_t)s * CHUNK;
#pragma unroll
    for (int i = 0; i < 4; ++i) {
      stage1k(gAh + so + i * 1024, Ahi + woff + i * 1024, lane);
      stage1k(gBh + so + i * 1024, Bhi + woff + i * 1024, lane);
    }
    __syncthreads();

#pragma unroll
    for (int ks = 0; ks < 2; ++ks) {
      const int kb = ks * 64 + (lane >> 4) * 16;
      bfrag ah[4], bh[4];
#pragma unroll
      for (int m = 0; m < 4; ++m) {
        const int r = wr * 64 + m * 16 + (lane & 15);
        ah[m] = *reinterpret_cast<const bfrag*>(Ahi + r * 128 + SWZ(r, kb));
      }
#pragma unroll
      for (int n2 = 0; n2 < 4; ++n2) {
        const int r = wc * 64 + n2 * 16 + (lane & 15);
        bh[n2] = *reinterpret_cast<const bfrag*>(Bhi + r * 128 + SWZ(r, kb));
      }
#pragma unroll
      for (int m = 0; m < 4; ++m)
#pragma unroll
        for (int n2 = 0; n2 < 4; ++n2)
          acc[m][n2] = __builtin_amdgcn_mfma_f32_16x16x32_bf16(ah[m], bh[n2], acc[m][n2], 0, 0, 0);
    }
    __syncthreads();
  }

  const int Ro = by * BM, Co = bx * BM;
  const int col = lane & 15, rq = (lane >> 4) * 4;
#pragma unroll
  for (int m = 0; m < 4; ++m)
#pragma unroll
    for (int n2 = 0; n2 < 4; ++n2) {
      const int gr = Ro + wr * 64 + m * 16 + rq;
      const int gc = Co + wc * 64 + n2 * 16 + col;
#pragma unroll
      for (int j = 0; j < 4; ++j)
        out[(size_t)(gr + j) * N_CTX + gc] = acc[m][n2][j];
      if (bx != by) {
        *reinterpret_cast<float4*>(out + (size_t)gc * N_CTX + gr) =
            make_float4(acc[m][n2][0], acc[m][n2][1], acc[m][n2][2], acc[m][n2][3]);
      }
    }
}

// ---------------------------------------------------------------------------
// Kernel 2 (fallback): on-the-fly split + 3-product MFMA (ws too small path).
// ---------------------------------------------------------------------------
__device__ __forceinline__ void stage_half(char* __restrict__ hi_base,
                                           char* __restrict__ lo_base,
                                           const float4* cv, const float4* wv,
                                           float s, int r, int h) {
  unsigned hu[16], lu[16];
#pragma unroll
  for (int i = 0; i < 8; ++i) {
    float f[4] = {cv[i].x * wv[i].x * s, cv[i].y * wv[i].y * s,
                  cv[i].z * wv[i].z * s, cv[i].w * wv[i].w * s};
    unsigned hb[4], lb[4];
#pragma unroll
    for (int j = 0; j < 4; ++j) {
      hb[j] = f2bf(f[j]);
      float hf = __uint_as_float(hb[j] << 16);
      lb[j] = f2bf(f[j] - hf);
    }
    hu[2 * i] = hb[0] | (hb[1] << 16);
    hu[2 * i + 1] = hb[2] | (hb[3] << 16);
    lu[2 * i] = lb[0] | (lb[1] << 16);
    lu[2 * i + 1] = lb[2] | (lb[3] << 16);
  }
#pragma unroll
  for (int c = 0; c < 4; ++c) {
    int boff = r * 128 + SWZ(r, h * 64 + c * 16);
    *reinterpret_cast<uint4*>(hi_base + boff) =
        make_uint4(hu[4 * c], hu[4 * c + 1], hu[4 * c + 2], hu[4 * c + 3]);
    *reinterpret_cast<uint4*>(lo_base + boff) =
        make_uint4(lu[4 * c], lu[4 * c + 1], lu[4 * c + 2], lu[4 * c + 3]);
  }
}

__global__ __launch_bounds__(256, 2) void att_gemm(
    const float* __restrict__ ctx, const float* __restrict__ w,
    const float* __restrict__ invr, float* __restrict__ out) {
  const int bx = blockIdx.x, by = blockIdx.y;
  if (by > bx) return;

  __shared__ __align__(16) char Ahi[BM * 128];
  __shared__ __align__(16) char Alo[BM * 128];
  __shared__ __align__(16) char Bhi[BM * 128];
  __shared__ __align__(16) char Blo[BM * 128];

  const int t = threadIdx.x;
  const int lane = t & 63, wid = t >> 6;
  const int wr = wid >> 1, wc = wid & 1;
  const int Ro = by * BM, Co = bx * BM;
  const int srow = t >> 1;
  const int sh = t & 1;

  f32x4 acc[4][4] = {};

  for (int k0 = 0; k0 < KTOT; k0 += BK) {
    const int p = k0 >> 9;
    const int d0 = (k0 & (DIM - 1)) + sh * 32;

    float4 cva[8], cvb[8], wv[8];
    const float* wrow = w + (size_t)p * DIM + d0;
    const float* arow = ctx + (size_t)(Ro + srow) * DIM + d0;
    const float* brow = ctx + (size_t)(Co + srow) * DIM + d0;
#pragma unroll
    for (int i = 0; i < 8; ++i) {
      wv[i] = *reinterpret_cast<const float4*>(wrow + 4 * i);
      cva[i] = *reinterpret_cast<const float4*>(arow + 4 * i);
      cvb[i] = *reinterpret_cast<const float4*>(brow + 4 * i);
    }
    const float sA = invr[(size_t)p * N_CTX + Ro + srow];
    const float sB = invr[(size_t)p * N_CTX + Co + srow];

    __syncthreads();
    stage_half(Ahi, Alo, cva, wv, sA, srow, sh);
    stage_half(Bhi, Blo, cvb, wv, sB, srow, sh);
    __syncthreads();

#pragma unroll
    for (int ks = 0; ks < 2; ++ks) {
      const int kb = ks * 64 + (lane >> 4) * 16;
      bfrag ah[4], al[4], bh[4], bl[4];
#pragma unroll
      for (int m = 0; m < 4; ++m) {
        const int r = wr * 64 + m * 16 + (lane & 15);
        const int off = r * 128 + SWZ(r, kb);
        ah[m] = *reinterpret_cast<const bfrag*>(Ahi + off);
        al[m] = *reinterpret_cast<const bfrag*>(Alo + off);
      }
#pragma unroll
      for (int n = 0; n < 4; ++n) {
        const int r = wc * 64 + n * 16 + (lane & 15);
        const int off = r * 128 + SWZ(r, kb);
        bh[n] = *reinterpret_cast<const bfrag*>(Bhi + off);
        bl[n] = *reinterpret_cast<const bfrag*>(Blo + off);
      }
#pragma unroll
      for (int m = 0; m < 4; ++m)
#pragma unroll
        for (int n = 0; n < 4; ++n) {
          acc[m][n] = __builtin_amdgcn_mfma_f32_16x16x32_bf16(ah[m], bh[n], acc[m][n], 0, 0, 0);
          acc[m][n] = __builtin_amdgcn_mfma_f32_16x16x32_bf16(ah[m], bl[n], acc[m][n], 0, 0, 0);
          acc[m][n] = __builtin_amdgcn_mfma_f32_16x16x32_bf16(al[m], bh[n], acc[m][n], 0, 0, 0);
        }
    }
  }

  const int col = lane & 15, rq = (lane >> 4) * 4;
#pragma unroll
  for (int m = 0; m < 4; ++m)
#pragma unroll
    for (int n = 0; n < 4; ++n) {
      const int gr = Ro + wr * 64 + m * 16 + rq;
      const int gc = Co + wc * 64 + n * 16 + col;
#pragma unroll
      for (int j = 0; j < 4; ++j)
        out[(size_t)(gr + j) * N_CTX + gc] = acc[m][n][j];
      if (bx != by) {
        *reinterpret_cast<float4*>(out + (size_t)gc * N_CTX + gr) =
            make_float4(acc[m][n][0], acc[m][n][1], acc[m][n][2], acc[m][n][3]);
      }
    }
}

// ---------------------------------------------------------------------------
// Kernel 3: scan — UNCHANGED from R17 (stores candV + nearEps flag).
// ---------------------------------------------------------------------------
__global__ __launch_bounds__(256) void topk_scan(
    float* __restrict__ att, int* __restrict__ candM,
    float* __restrict__ candV, int* __restrict__ cnt_g) {
  __shared__ unsigned red[2][4];
  __shared__ int lcnt, lg;

  const int n = blockIdx.x;
  const int t = threadIdx.x;
  const int wid = t >> 6, lane = t & 63;
  float* row = att + (size_t)n * N_CTX;

  float ar[16], tr[16];
  unsigned ur[16];
#pragma unroll
  for (int i = 0; i < 4; ++i) {
    float4 v4 = *reinterpret_cast<const float4*>(row + (size_t)(i * 256 + t) * 4);
    float tmp[4] = {v4.x, v4.y, v4.z, v4.w};
#pragma unroll
    for (int j = 0; j < 4; ++j) {
      float a = tmp[j];
      float tt = (a > EPS_NN) ? a : 0.0f;
      ar[i * 4 + j] = a;
      tr[i * 4 + j] = tt;
      ur[i * 4 + j] = __float_as_uint(tt);
    }
  }
  if (t == 0) { lcnt = 0; lg = 0; }

  unsigned lo = 0u, hi = 0x7F800000u;
  int buf = 0;
  while (lo < hi) {
    unsigned mid = lo + ((hi - lo) >> 1);
    unsigned c = 0;
#pragma unroll
    for (int i = 0; i < 16; ++i) c += (ur[i] > mid) ? 1u : 0u;
#pragma unroll
    for (int off = 32; off; off >>= 1) c += __shfl_down(c, off, 64);
    if (lane == 0) red[buf][wid] = c;
    __syncthreads();
    unsigned tot = red[buf][0] + red[buf][1] + red[buf][2] + red[buf][3];
    if (tot < TOPK_K) hi = mid; else lo = mid + 1;
    buf ^= 1;
  }
  const float vk = __uint_as_float(lo);
  const bool nearEps = (vk <= EPS_NN + 2.0f * DELTA);
  __syncthreads();   // lcnt/lg init visible

  unsigned myg = 0;
#pragma unroll
  for (int i = 0; i < 16; ++i) {
    const int blk = i >> 2, j = i & 3;
    const int m = (blk * 256 + t) * 4 + j;
    const float a = ar[i], tt = tr[i];
    const bool isEps = fabsf(a - EPS_NN) <= DELTA;
    const bool isOrd = (tt > 0.f) && (fabsf(tt - vk) <= DELTA);
    const bool cand = isOrd || (isEps && nearEps);
    const bool defIn = (tt > vk + DELTA) && !cand;
    tr[i] = defIn ? tt : 0.f;
    myg += defIn ? 1u : 0u;
    unsigned long long mask = __ballot(cand);
    if (mask) {
      int base = 0;
      if (lane == 0) base = atomicAdd(&lcnt, (int)__popcll(mask));
      base = __shfl(base, 0, 64);
      if (cand) {
        int pos = base + (int)__popcll(mask & ((1ull << lane) - 1ull));
        if (pos < CAP) {
          candM[n * CAP + pos] = m;
          candV[n * CAP + pos] = tt;
        }
      }
    }
  }
#pragma unroll
  for (int off = 32; off; off >>= 1) myg += __shfl_down(myg, off, 64);
  if (lane == 0) atomicAdd(&lg, (int)myg);

#pragma unroll
  for (int i = 0; i < 4; ++i) {
    *reinterpret_cast<float4*>(row + (size_t)(i * 256 + t) * 4) =
        make_float4(tr[i * 4], tr[i * 4 + 1], tr[i * 4 + 2], tr[i * 4 + 3]);
  }
  __syncthreads();
  if (t == 0) {
    cnt_g[4 * n] = (lcnt < CAP) ? lcnt : CAP;
    cnt_g[4 * n + 1] = lg;
    cnt_g[4 * n + 2] = nearEps ? 1 : 0;
  }
}

// ---------------------------------------------------------------------------
// Kernel 4: exact repair + select. R18 = R16's lane-per-candidate global-load
// body (450 us validated; NO LDS staging — R17's restructure regressed 2.5x)
// + the skip-path head: c == slots && !nearEps -> all candidates provably in
// the exact top-30, approx values OK (err <= ~3e-5 << 2e-2), no chain.
// ---------------------------------------------------------------------------
__global__ __launch_bounds__(64) void repair_select(
    const float* __restrict__ ctx, const float* __restrict__ w,
    const float* __restrict__ invr, const int* __restrict__ candM,
    const float* __restrict__ candV, const int* __restrict__ cnt_g,
    float* __restrict__ att) {
  const int n = blockIdx.x;
  const int c = cnt_g[4 * n];
  if (c == 0) return;
  const int slots = TOPK_K - cnt_g[4 * n + 1];
  const int nearEps = cnt_g[4 * n + 2];
  const int j = threadIdx.x;

  if (c <= slots && !nearEps) {   // all candidates selected; approx values OK
    if (j < c) att[(size_t)n * N_CTX + candM[n * CAP + j]] = candV[n * CAP + j];
    return;
  }

  __shared__ float te_s[CAP];
  __shared__ int m_s[CAP];

  float te = -1.f;
  int m = -1;
  if (j < c) {
    m = candM[n * CAP + j];
    const float4* cn4 = reinterpret_cast<const float4*>(ctx + (size_t)n * DIM);
    const float4* cm4 = reinterpret_cast<const float4*>(ctx + (size_t)m * DIM);
    float e = 0.f;
    for (int p = 0; p < NPERS; ++p) {
      const float sA = invr[(size_t)p * N_CTX + n];
      const float sB = invr[(size_t)p * N_CTX + m];
      const float4* w4 = reinterpret_cast<const float4*>(w + (size_t)p * DIM);
#pragma unroll 4
      for (int q = 0; q < DIM / 4; ++q) {
        const float4 a = cn4[q], b = cm4[q], ww = w4[q];
        e = fmaf((a.x * ww.x) * sA, (b.x * ww.x) * sB, e);
        e = fmaf((a.y * ww.y) * sA, (b.y * ww.y) * sB, e);
        e = fmaf((a.z * ww.z) * sA, (b.z * ww.z) * sB, e);
        e = fmaf((a.w * ww.w) * sA, (b.w * ww.w) * sB, e);
      }
    }
    te = (e > EPS_NN) ? e : 0.f;
  }
  m_s[j] = m;
  te_s[j] = te;
  __syncthreads();
  if (j < c) {
    int rank = 0;
    for (int i = 0; i < c; ++i) {
      if (i == j) continue;
      rank += ((te_s[i] > te) || (te_s[i] == te && m_s[i] < m)) ? 1 : 0;
    }
    if (rank < slots) att[(size_t)n * N_CTX + m] = te;
  }
}

// ---------------------------------------------------------------------------
extern "C" void kernel_launch(void* const* d_in, const int* in_sizes, int n_in,
                              void* d_out, int out_size, void* d_ws, size_t ws_size,
                              hipStream_t stream) {
  const float* ctx = (const float*)d_in[0];   // (4096, 512)
  const float* w   = (const float*)d_in[1];   // (16, 512)
  float* out = (float*)d_out;                 // (4096, 4096)

  // ws: invr 256KB | cnt_g 64KB | candM 1MB | candV 1MB | Fhi 64MB
  const size_t OFF_CNT = 262144;
  const size_t OFF_CAND = OFF_CNT + 65536;
  const size_t OFF_CV = OFF_CAND + 1048576;
  const size_t OFF_FHI = OFF_CV + 1048576;
  const size_t FSZ = (size_t)32 * NKSTEP * CHUNK;       // 67108864
  float* invr = (float*)d_ws;
  int* cnt_g = (int*)((char*)d_ws + OFF_CNT);
  int* candM = (int*)((char*)d_ws + OFF_CAND);
  float* candV = (float*)((char*)d_ws + OFF_CV);
  unsigned short* Fhi = (unsigned short*)((char*)d_ws + OFF_FHI);
  const bool haveF = ws_size >= OFF_FHI + FSZ;

  if (haveF) {
    split_norms_kernel<<<(N_CTX * 64) / 256, 256, 0, stream>>>(ctx, w, invr, Fhi);
    att_gemm_fast<<<528, 256, 0, stream>>>(Fhi, out);
  } else {
    norms_kernel<<<(NPERS * N_CTX) / 4, 256, 0, stream>>>(ctx, w, invr);
    dim3 grid(N_CTX / BM, N_CTX / BM);
    att_gemm<<<grid, 256, 0, stream>>>(ctx, w, invr, out);
  }

  topk_scan<<<N_CTX, 256, 0, stream>>>(out, candM, candV, cnt_g);
  repair_select<<<N_CTX, 64, 0, stream>>>(ctx, w, invr, candM, candV, cnt_g, out);
}

// Round 19
// 668.076 us; speedup vs baseline: 1.9757x; 1.0241x over previous
//
#include <hip/hip_runtime.h>
#include <math.h>
#include <stdint.h>

#define N_CTX 4096
#define DIM 512
#define NPERS 16
#define KTOT (NPERS * DIM)   // 8192
#define EPS_NN 0.1f
#define TOPK_K 30

#define DELTA 4e-4f          // ambiguity margin. GEMM-vs-chain error max ~3e-5
                             // over 16.7M elems -> >=6x margin at 4e-4.
#define CAP 64               // max candidates per row

#define BM 128               // MFMA output tile
#define BK 64                // K-step (bf16 elems)
#define NKSTEP (KTOT / BK)   // 128
#define CHUNK 16384          // bytes per (panel, k-step) LDS image

typedef __attribute__((ext_vector_type(8))) short bfrag;   // 8 bf16 = 4 VGPR
typedef __attribute__((ext_vector_type(4))) float f32x4;

// round-to-nearest-even float -> bf16 bits
__device__ __forceinline__ unsigned short f2bf(float f) {
  unsigned u = __float_as_uint(f);
  unsigned r = u + 0x7FFFu + ((u >> 16) & 1u);
  return (unsigned short)(r >> 16);
}

#define SWZ(r, b) ((b) ^ (((r) & 7) << 4))

// stage 1 KB: 64 lanes x 16 B. ldst = wave-uniform LDS base; HW adds lane*16.
__device__ __forceinline__ void stage1k(const char* gsrc, char* ldst, int lane) {
#if __has_builtin(__builtin_amdgcn_global_load_lds)
  __builtin_amdgcn_global_load_lds(
      (const __attribute__((address_space(1))) unsigned int*)(uintptr_t)(gsrc + lane * 16),
      (__attribute__((address_space(3))) unsigned int*)(uintptr_t)ldst, 16, 0, 0);
#else
  *reinterpret_cast<uint4*>(ldst + lane * 16) =
      *reinterpret_cast<const uint4*>(gsrc + lane * 16);
#endif
}

// ---------------------------------------------------------------------------
// Kernel 1 (fallback only): invr[p][n] = 0.25 / max(||c_n * w_p||, 1e-12)
// ---------------------------------------------------------------------------
__global__ __launch_bounds__(256) void norms_kernel(
    const float* __restrict__ ctx, const float* __restrict__ w,
    float* __restrict__ invr) {
  int wid = threadIdx.x >> 6;
  int lane = threadIdx.x & 63;
  int gid = blockIdx.x * 4 + wid;          // 0 .. 65535
  int p = gid >> 12;
  int n = gid & (N_CTX - 1);
  const float4* c4 = reinterpret_cast<const float4*>(ctx + (size_t)n * DIM + lane * 8);
  const float4* w4 = reinterpret_cast<const float4*>(w + (size_t)p * DIM + lane * 8);
  float4 c0 = c4[0], c1 = c4[1];
  float4 w0 = w4[0], w1 = w4[1];
  float s = 0.f, v;
  v = c0.x * w0.x; s = fmaf(v, v, s);
  v = c0.y * w0.y; s = fmaf(v, v, s);
  v = c0.z * w0.z; s = fmaf(v, v, s);
  v = c0.w * w0.w; s = fmaf(v, v, s);
  v = c1.x * w1.x; s = fmaf(v, v, s);
  v = c1.y * w1.y; s = fmaf(v, v, s);
  v = c1.z * w1.z; s = fmaf(v, v, s);
  v = c1.w * w1.w; s = fmaf(v, v, s);
#pragma unroll
  for (int off = 32; off; off >>= 1) s += __shfl_down(s, off, 64);
  if (lane == 0) invr[(size_t)p * N_CTX + n] = 0.25f / fmaxf(sqrtf(s), 1e-12f);
}

// ---------------------------------------------------------------------------
// Kernel 1+1b FUSED: norms (bit-identical chain) + bf16-hi split into the
// panel-swizzled LDS-image layout. UNCHANGED from R16-R18.
// ---------------------------------------------------------------------------
__global__ __launch_bounds__(256) void split_norms_kernel(
    const float* __restrict__ ctx, const float* __restrict__ w,
    float* __restrict__ invr, unsigned short* __restrict__ Fhi) {
  const int tid = blockIdx.x * 256 + threadIdx.x;   // 0 .. 4096*64-1
  const int n = tid >> 6;                 // wave-uniform (wave = 64 aligned)
  const int db = tid & 63;                // lane = 8-col block within 512-dim
  const int d0 = db * 8;
  const int P = n >> 7;                   // panel
  const int r = n & 127;                  // row within panel
  const int sl = db & 7;                  // 16B slot within k-step chunk
  const int swzoff = r * 128 + ((sl * 16) ^ ((r & 7) << 4));

  const float4 c0 = *reinterpret_cast<const float4*>(ctx + (size_t)n * DIM + d0);
  const float4 c1 = *reinterpret_cast<const float4*>(ctx + (size_t)n * DIM + d0 + 4);

#pragma unroll
  for (int p = 0; p < NPERS; ++p) {
    const float4 w0 = *reinterpret_cast<const float4*>(w + (size_t)p * DIM + d0);
    const float4 w1 = *reinterpret_cast<const float4*>(w + (size_t)p * DIM + d0 + 4);

    float pr[8] = {c0.x * w0.x, c0.y * w0.y, c0.z * w0.z, c0.w * w0.w,
                   c1.x * w1.x, c1.y * w1.y, c1.z * w1.z, c1.w * w1.w};

    float s = 0.f;
#pragma unroll
    for (int j = 0; j < 8; ++j) s = fmaf(pr[j], pr[j], s);
#pragma unroll
    for (int off = 32; off; off >>= 1) s += __shfl_down(s, off, 64);
    const float stot = __shfl(s, 0, 64);
    const float sc = 0.25f / fmaxf(sqrtf(stot), 1e-12f);
    if (db == 0) invr[(size_t)p * N_CTX + n] = sc;

    unsigned hb[8];
#pragma unroll
    for (int j = 0; j < 8; ++j) hb[j] = f2bf(pr[j] * sc);   // == (c*w)*sc
    uint4 hv = make_uint4(hb[0] | (hb[1] << 16), hb[2] | (hb[3] << 16),
                          hb[4] | (hb[5] << 16), hb[6] | (hb[7] << 16));
    const int kstep = p * 8 + (db >> 3);           // k-step index
    const size_t base = (size_t)(P * 128 + kstep) * CHUNK + swzoff;
    *reinterpret_cast<uint4*>((char*)Fhi + base) = hv;
  }
}

// ---------------------------------------------------------------------------
// Kernel 2 (fast): att ~= Fhi Fhi^T via bf16 MFMA, SINGLE product.
// UNCHANGED from R16 (validated).
// ---------------------------------------------------------------------------
__global__ __launch_bounds__(256, 3) void att_gemm_fast(
    const unsigned short* __restrict__ Fhi, float* __restrict__ out) {
  const int bid0 = blockIdx.x;
  int bid = (bid0 & 7) * 66 + (bid0 >> 3);   // XCD-contiguous tile runs
  int by = 0;
  while (bid >= (by + 1) * 32 - ((by + 1) * by) / 2) ++by;
  const int bx = by + (bid - (by * 32 - (by * (by - 1)) / 2));

  __shared__ __align__(16) char Ahi[CHUNK];
  __shared__ __align__(16) char Bhi[CHUNK];

  const int t = threadIdx.x;
  const int lane = t & 63, wid = t >> 6;
  const int wr = wid >> 1, wc = wid & 1;
  const int woff = __builtin_amdgcn_readfirstlane(wid * 4096);

  const char* gAh = (const char*)Fhi + (size_t)by * NKSTEP * CHUNK + woff;
  const char* gBh = (const char*)Fhi + (size_t)bx * NKSTEP * CHUNK + woff;

  f32x4 acc[4][4] = {};

  for (int s = 0; s < NKSTEP; ++s) {
    const size_t so = (size_t)s * CHUNK;
#pragma unroll
    for (int i = 0; i < 4; ++i) {
      stage1k(gAh + so + i * 1024, Ahi + woff + i * 1024, lane);
      stage1k(gBh + so + i * 1024, Bhi + woff + i * 1024, lane);
    }
    __syncthreads();

#pragma unroll
    for (int ks = 0; ks < 2; ++ks) {
      const int kb = ks * 64 + (lane >> 4) * 16;
      bfrag ah[4], bh[4];
#pragma unroll
      for (int m = 0; m < 4; ++m) {
        const int r = wr * 64 + m * 16 + (lane & 15);
        ah[m] = *reinterpret_cast<const bfrag*>(Ahi + r * 128 + SWZ(r, kb));
      }
#pragma unroll
      for (int n2 = 0; n2 < 4; ++n2) {
        const int r = wc * 64 + n2 * 16 + (lane & 15);
        bh[n2] = *reinterpret_cast<const bfrag*>(Bhi + r * 128 + SWZ(r, kb));
      }
#pragma unroll
      for (int m = 0; m < 4; ++m)
#pragma unroll
        for (int n2 = 0; n2 < 4; ++n2)
          acc[m][n2] = __builtin_amdgcn_mfma_f32_16x16x32_bf16(ah[m], bh[n2], acc[m][n2], 0, 0, 0);
    }
    __syncthreads();
  }

  const int Ro = by * BM, Co = bx * BM;
  const int col = lane & 15, rq = (lane >> 4) * 4;
#pragma unroll
  for (int m = 0; m < 4; ++m)
#pragma unroll
    for (int n2 = 0; n2 < 4; ++n2) {
      const int gr = Ro + wr * 64 + m * 16 + rq;
      const int gc = Co + wc * 64 + n2 * 16 + col;
#pragma unroll
      for (int j = 0; j < 4; ++j)
        out[(size_t)(gr + j) * N_CTX + gc] = acc[m][n2][j];
      if (bx != by) {
        *reinterpret_cast<float4*>(out + (size_t)gc * N_CTX + gr) =
            make_float4(acc[m][n2][0], acc[m][n2][1], acc[m][n2][2], acc[m][n2][3]);
      }
    }
}

// ---------------------------------------------------------------------------
// Kernel 2 (fallback): on-the-fly split + 3-product MFMA (ws too small path).
// ---------------------------------------------------------------------------
__device__ __forceinline__ void stage_half(char* __restrict__ hi_base,
                                           char* __restrict__ lo_base,
                                           const float4* cv, const float4* wv,
                                           float s, int r, int h) {
  unsigned hu[16], lu[16];
#pragma unroll
  for (int i = 0; i < 8; ++i) {
    float f[4] = {cv[i].x * wv[i].x * s, cv[i].y * wv[i].y * s,
                  cv[i].z * wv[i].z * s, cv[i].w * wv[i].w * s};
    unsigned hb[4], lb[4];
#pragma unroll
    for (int j = 0; j < 4; ++j) {
      hb[j] = f2bf(f[j]);
      float hf = __uint_as_float(hb[j] << 16);
      lb[j] = f2bf(f[j] - hf);
    }
    hu[2 * i] = hb[0] | (hb[1] << 16);
    hu[2 * i + 1] = hb[2] | (hb[3] << 16);
    lu[2 * i] = lb[0] | (lb[1] << 16);
    lu[2 * i + 1] = lb[2] | (lb[3] << 16);
  }
#pragma unroll
  for (int c = 0; c < 4; ++c) {
    int boff = r * 128 + SWZ(r, h * 64 + c * 16);
    *reinterpret_cast<uint4*>(hi_base + boff) =
        make_uint4(hu[4 * c], hu[4 * c + 1], hu[4 * c + 2], hu[4 * c + 3]);
    *reinterpret_cast<uint4*>(lo_base + boff) =
        make_uint4(lu[4 * c], lu[4 * c + 1], lu[4 * c + 2], lu[4 * c + 3]);
  }
}

__global__ __launch_bounds__(256, 2) void att_gemm(
    const float* __restrict__ ctx, const float* __restrict__ w,
    const float* __restrict__ invr, float* __restrict__ out) {
  const int bx = blockIdx.x, by = blockIdx.y;
  if (by > bx) return;

  __shared__ __align__(16) char Ahi[BM * 128];
  __shared__ __align__(16) char Alo[BM * 128];
  __shared__ __align__(16) char Bhi[BM * 128];
  __shared__ __align__(16) char Blo[BM * 128];

  const int t = threadIdx.x;
  const int lane = t & 63, wid = t >> 6;
  const int wr = wid >> 1, wc = wid & 1;
  const int Ro = by * BM, Co = bx * BM;
  const int srow = t >> 1;
  const int sh = t & 1;

  f32x4 acc[4][4] = {};

  for (int k0 = 0; k0 < KTOT; k0 += BK) {
    const int p = k0 >> 9;
    const int d0 = (k0 & (DIM - 1)) + sh * 32;

    float4 cva[8], cvb[8], wv[8];
    const float* wrow = w + (size_t)p * DIM + d0;
    const float* arow = ctx + (size_t)(Ro + srow) * DIM + d0;
    const float* brow = ctx + (size_t)(Co + srow) * DIM + d0;
#pragma unroll
    for (int i = 0; i < 8; ++i) {
      wv[i] = *reinterpret_cast<const float4*>(wrow + 4 * i);
      cva[i] = *reinterpret_cast<const float4*>(arow + 4 * i);
      cvb[i] = *reinterpret_cast<const float4*>(brow + 4 * i);
    }
    const float sA = invr[(size_t)p * N_CTX + Ro + srow];
    const float sB = invr[(size_t)p * N_CTX + Co + srow];

    __syncthreads();
    stage_half(Ahi, Alo, cva, wv, sA, srow, sh);
    stage_half(Bhi, Blo, cvb, wv, sB, srow, sh);
    __syncthreads();

#pragma unroll
    for (int ks = 0; ks < 2; ++ks) {
      const int kb = ks * 64 + (lane >> 4) * 16;
      bfrag ah[4], al[4], bh[4], bl[4];
#pragma unroll
      for (int m = 0; m < 4; ++m) {
        const int r = wr * 64 + m * 16 + (lane & 15);
        const int off = r * 128 + SWZ(r, kb);
        ah[m] = *reinterpret_cast<const bfrag*>(Ahi + off);
        al[m] = *reinterpret_cast<const bfrag*>(Alo + off);
      }
#pragma unroll
      for (int n = 0; n < 4; ++n) {
        const int r = wc * 64 + n * 16 + (lane & 15);
        const int off = r * 128 + SWZ(r, kb);
        bh[n] = *reinterpret_cast<const bfrag*>(Bhi + off);
        bl[n] = *reinterpret_cast<const bfrag*>(Blo + off);
      }
#pragma unroll
      for (int m = 0; m < 4; ++m)
#pragma unroll
        for (int n = 0; n < 4; ++n) {
          acc[m][n] = __builtin_amdgcn_mfma_f32_16x16x32_bf16(ah[m], bh[n], acc[m][n], 0, 0, 0);
          acc[m][n] = __builtin_amdgcn_mfma_f32_16x16x32_bf16(ah[m], bl[n], acc[m][n], 0, 0, 0);
          acc[m][n] = __builtin_amdgcn_mfma_f32_16x16x32_bf16(al[m], bh[n], acc[m][n], 0, 0, 0);
        }
    }
  }

  const int col = lane & 15, rq = (lane >> 4) * 4;
#pragma unroll
  for (int m = 0; m < 4; ++m)
#pragma unroll
    for (int n = 0; n < 4; ++n) {
      const int gr = Ro + wr * 64 + m * 16 + rq;
      const int gc = Co + wc * 64 + n * 16 + col;
#pragma unroll
      for (int j = 0; j < 4; ++j)
        out[(size_t)(gr + j) * N_CTX + gc] = acc[m][n][j];
      if (bx != by) {
        *reinterpret_cast<float4*>(out + (size_t)gc * N_CTX + gr) =
            make_float4(acc[m][n][0], acc[m][n][1], acc[m][n][2], acc[m][n][3]);
      }
    }
}

// ---------------------------------------------------------------------------
// Kernel 3: scan — UNCHANGED from R17/R18 (stores candV + nearEps flag).
// ---------------------------------------------------------------------------
__global__ __launch_bounds__(256) void topk_scan(
    float* __restrict__ att, int* __restrict__ candM,
    float* __restrict__ candV, int* __restrict__ cnt_g) {
  __shared__ unsigned red[2][4];
  __shared__ int lcnt, lg;

  const int n = blockIdx.x;
  const int t = threadIdx.x;
  const int wid = t >> 6, lane = t & 63;
  float* row = att + (size_t)n * N_CTX;

  float ar[16], tr[16];
  unsigned ur[16];
#pragma unroll
  for (int i = 0; i < 4; ++i) {
    float4 v4 = *reinterpret_cast<const float4*>(row + (size_t)(i * 256 + t) * 4);
    float tmp[4] = {v4.x, v4.y, v4.z, v4.w};
#pragma unroll
    for (int j = 0; j < 4; ++j) {
      float a = tmp[j];
      float tt = (a > EPS_NN) ? a : 0.0f;
      ar[i * 4 + j] = a;
      tr[i * 4 + j] = tt;
      ur[i * 4 + j] = __float_as_uint(tt);
    }
  }
  if (t == 0) { lcnt = 0; lg = 0; }

  unsigned lo = 0u, hi = 0x7F800000u;
  int buf = 0;
  while (lo < hi) {
    unsigned mid = lo + ((hi - lo) >> 1);
    unsigned c = 0;
#pragma unroll
    for (int i = 0; i < 16; ++i) c += (ur[i] > mid) ? 1u : 0u;
#pragma unroll
    for (int off = 32; off; off >>= 1) c += __shfl_down(c, off, 64);
    if (lane == 0) red[buf][wid] = c;
    __syncthreads();
    unsigned tot = red[buf][0] + red[buf][1] + red[buf][2] + red[buf][3];
    if (tot < TOPK_K) hi = mid; else lo = mid + 1;
    buf ^= 1;
  }
  const float vk = __uint_as_float(lo);
  const bool nearEps = (vk <= EPS_NN + 2.0f * DELTA);
  __syncthreads();   // lcnt/lg init visible

  unsigned myg = 0;
#pragma unroll
  for (int i = 0; i < 16; ++i) {
    const int blk = i >> 2, j = i & 3;
    const int m = (blk * 256 + t) * 4 + j;
    const float a = ar[i], tt = tr[i];
    const bool isEps = fabsf(a - EPS_NN) <= DELTA;
    const bool isOrd = (tt > 0.f) && (fabsf(tt - vk) <= DELTA);
    const bool cand = isOrd || (isEps && nearEps);
    const bool defIn = (tt > vk + DELTA) && !cand;
    tr[i] = defIn ? tt : 0.f;
    myg += defIn ? 1u : 0u;
    unsigned long long mask = __ballot(cand);
    if (mask) {
      int base = 0;
      if (lane == 0) base = atomicAdd(&lcnt, (int)__popcll(mask));
      base = __shfl(base, 0, 64);
      if (cand) {
        int pos = base + (int)__popcll(mask & ((1ull << lane) - 1ull));
        if (pos < CAP) {
          candM[n * CAP + pos] = m;
          candV[n * CAP + pos] = tt;
        }
      }
    }
  }
#pragma unroll
  for (int off = 32; off; off >>= 1) myg += __shfl_down(myg, off, 64);
  if (lane == 0) atomicAdd(&lg, (int)myg);

#pragma unroll
  for (int i = 0; i < 4; ++i) {
    *reinterpret_cast<float4*>(row + (size_t)(i * 256 + t) * 4) =
        make_float4(tr[i * 4], tr[i * 4 + 1], tr[i * 4 + 2], tr[i * 4 + 3]);
  }
  __syncthreads();
  if (t == 0) {
    cnt_g[4 * n] = (lcnt < CAP) ? lcnt : CAP;
    cnt_g[4 * n + 1] = lg;
    cnt_g[4 * n + 2] = nearEps ? 1 : 0;
  }
}

// ---------------------------------------------------------------------------
// Kernel 4: exact repair + select. R19:
//  - skip-path (R18, validated semantics)
//  - cooperative cache-warm of cn + candidate rows (coalesced; asm keeps
//    loads live per rule #17) so chain loads are L1/L2 hits
//  - depth-2 software-pipelined chain: prefetch group q+2 while computing
//    group q. fmaf sequence VERBATIM (same ops, same order -> bit-identical).
// ---------------------------------------------------------------------------
__global__ __launch_bounds__(64) void repair_select(
    const float* __restrict__ ctx, const float* __restrict__ w,
    const float* __restrict__ invr, const int* __restrict__ candM,
    const float* __restrict__ candV, const int* __restrict__ cnt_g,
    float* __restrict__ att) {
  const int n = blockIdx.x;
  const int c = cnt_g[4 * n];
  if (c == 0) return;
  const int slots = TOPK_K - cnt_g[4 * n + 1];
  const int nearEps = cnt_g[4 * n + 2];
  const int j = threadIdx.x;

  if (c <= slots && !nearEps) {   // all candidates selected; approx values OK
    if (j < c) att[(size_t)n * N_CTX + candM[n * CAP + j]] = candV[n * CAP + j];
    return;
  }

  __shared__ float te_s[CAP];
  __shared__ int m_s[CAP];
  if (j < c) m_s[j] = candM[n * CAP + j];
  __syncthreads();

  // cooperative cache-warm: coalesced touch of cn row + all candidate rows
  {
    const float* cn = ctx + (size_t)n * DIM + j * 8;
    float4 t0 = *reinterpret_cast<const float4*>(cn);
    float4 t1 = *reinterpret_cast<const float4*>(cn + 4);
    asm volatile("" :: "v"(t0.x), "v"(t1.x));
    for (int i = 0; i < c; ++i) {
      const float* cm = ctx + (size_t)m_s[i] * DIM + j * 8;
      float4 u0 = *reinterpret_cast<const float4*>(cm);
      float4 u1 = *reinterpret_cast<const float4*>(cm + 4);
      asm volatile("" :: "v"(u0.x), "v"(u1.x));
    }
  }

  float te = -1.f;
  int m = -1;
  if (j < c) {
    m = m_s[j];
    const float4* cn4 = reinterpret_cast<const float4*>(ctx + (size_t)n * DIM);
    const float4* cm4 = reinterpret_cast<const float4*>(ctx + (size_t)m * DIM);
    float e = 0.f;
    for (int p = 0; p < NPERS; ++p) {
      const float sA = invr[(size_t)p * N_CTX + n];
      const float sB = invr[(size_t)p * N_CTX + m];
      const float4* w4 = reinterpret_cast<const float4*>(w + (size_t)p * DIM);
      // depth-2 pipelined: named rotating registers (rule #20: static idx)
      float4 a0 = cn4[0], b0 = cm4[0], g0 = w4[0];
      float4 a1 = cn4[1], b1 = cm4[1], g1 = w4[1];
#pragma unroll 2
      for (int q = 0; q < DIM / 4 - 2; ++q) {
        float4 a2 = cn4[q + 2], b2 = cm4[q + 2], g2 = w4[q + 2];
        e = fmaf((a0.x * g0.x) * sA, (b0.x * g0.x) * sB, e);
        e = fmaf((a0.y * g0.y) * sA, (b0.y * g0.y) * sB, e);
        e = fmaf((a0.z * g0.z) * sA, (b0.z * g0.z) * sB, e);
        e = fmaf((a0.w * g0.w) * sA, (b0.w * g0.w) * sB, e);
        a0 = a1; b0 = b1; g0 = g1;
        a1 = a2; b1 = b2; g1 = g2;
      }
      // epilogue: groups DIM/4-2 and DIM/4-1 (held in a0/a1)
      e = fmaf((a0.x * g0.x) * sA, (b0.x * g0.x) * sB, e);
      e = fmaf((a0.y * g0.y) * sA, (b0.y * g0.y) * sB, e);
      e = fmaf((a0.z * g0.z) * sA, (b0.z * g0.z) * sB, e);
      e = fmaf((a0.w * g0.w) * sA, (b0.w * g0.w) * sB, e);
      e = fmaf((a1.x * g1.x) * sA, (b1.x * g1.x) * sB, e);
      e = fmaf((a1.y * g1.y) * sA, (b1.y * g1.y) * sB, e);
      e = fmaf((a1.z * g1.z) * sA, (b1.z * g1.z) * sB, e);
      e = fmaf((a1.w * g1.w) * sA, (b1.w * g1.w) * sB, e);
    }
    te = (e > EPS_NN) ? e : 0.f;
  }
  m_s[j] = m;
  te_s[j] = te;
  __syncthreads();
  if (j < c) {
    int rank = 0;
    for (int i = 0; i < c; ++i) {
      if (i == j) continue;
      rank += ((te_s[i] > te) || (te_s[i] == te && m_s[i] < m)) ? 1 : 0;
    }
    if (rank < slots) att[(size_t)n * N_CTX + m] = te;
  }
}

// ---------------------------------------------------------------------------
extern "C" void kernel_launch(void* const* d_in, const int* in_sizes, int n_in,
                              void* d_out, int out_size, void* d_ws, size_t ws_size,
                              hipStream_t stream) {
  const float* ctx = (const float*)d_in[0];   // (4096, 512)
  const float* w   = (const float*)d_in[1];   // (16, 512)
  float* out = (float*)d_out;                 // (4096, 4096)

  // ws: invr 256KB | cnt_g 64KB | candM 1MB | candV 1MB | Fhi 64MB
  const size_t OFF_CNT = 262144;
  const size_t OFF_CAND = OFF_CNT + 65536;
  const size_t OFF_CV = OFF_CAND + 1048576;
  const size_t OFF_FHI = OFF_CV + 1048576;
  const size_t FSZ = (size_t)32 * NKSTEP * CHUNK;       // 67108864
  float* invr = (float*)d_ws;
  int* cnt_g = (int*)((char*)d_ws + OFF_CNT);
  int* candM = (int*)((char*)d_ws + OFF_CAND);
  float* candV = (float*)((char*)d_ws + OFF_CV);
  unsigned short* Fhi = (unsigned short*)((char*)d_ws + OFF_FHI);
  const bool haveF = ws_size >= OFF_FHI + FSZ;

  if (haveF) {
    split_norms_kernel<<<(N_CTX * 64) / 256, 256, 0, stream>>>(ctx, w, invr, Fhi);
    att_gemm_fast<<<528, 256, 0, stream>>>(Fhi, out);
  } else {
    norms_kernel<<<(NPERS * N_CTX) / 4, 256, 0, stream>>>(ctx, w, invr);
    dim3 grid(N_CTX / BM, N_CTX / BM);
    att_gemm<<<grid, 256, 0, stream>>>(ctx, w, invr, out);
  }

  topk_scan<<<N_CTX, 256, 0, stream>>>(out, candM, candV, cnt_g);
  repair_select<<<N_CTX, 64, 0, stream>>>(ctx, w, invr, candM, candV, cnt_g, out);
}